// Round 17
// baseline (584.545 us; speedup 1.0000x reference)
//
#include <hip/hip_runtime.h>
#include <hip/hip_bf16.h>

// SimVQ: x[8,2048,512] f32, codebook[4096,512] f32, W[512,512] f32
// out (f32 flat): quantized_out[16384*512] | indices[16384] (as f32) | commit_loss[1]
//
// Round 17: r16 with ONE change — k_dist becomes r12's 256x256 tile with the
// double-buffer REMOVED: single 64 KB LDS -> 2 blocks/CU resident.
// Empirical law from r5-r16: wall ~= (grid x Ksteps / (256 x residency)) x 20k cyc;
// 256^2 @ 2 res -> 16 seq-steps vs r13's 37.6. Everything else r16 verbatim.

typedef unsigned short ushort_t;
typedef __attribute__((ext_vector_type(8))) short bf16x8;
typedef __attribute__((ext_vector_type(4))) float f32x4;

constexpr int D  = 512;
constexpr int C  = 4096;
constexpr int NR = 16384;
constexpr int NSL = 64;             // partial slices per row (row-major)
constexpr float DELTA = 1.0f;       // top-4 fp64 rescue threshold

__device__ __forceinline__ ushort_t f2bf(float v) {
  __hip_bfloat16 h = __float2bfloat16(v);
  return *reinterpret_cast<ushort_t*>(&h);
}
__device__ __forceinline__ float bf2f(ushort_t u) {
  __hip_bfloat16 h;
  *reinterpret_cast<ushort_t*>(&h) = u;
  return __bfloat162float(h);
}

__device__ __forceinline__ void gld16(void* lds, const void* g) {
  __builtin_amdgcn_global_load_lds(
      (const __attribute__((address_space(1))) unsigned int*)g,
      (__attribute__((address_space(3))) unsigned int*)lds, 16, 0, 0);
}

__device__ __forceinline__ bool lexlt(float v, int i, float ov, int oi) {
  return v < ov || (v == ov && i < oi);
}

__device__ __forceinline__ void top2_merge(float& v1, int& i1, float& v2, int& i2,
                                           float ov1, int oi1, float ov2, int oi2) {
  if (lexlt(ov1, oi1, v1, i1)) {
    float nv2; int ni2;
    if (lexlt(v1, i1, ov2, oi2)) { nv2 = v1; ni2 = i1; }
    else { nv2 = ov2; ni2 = oi2; }
    v2 = nv2; i2 = ni2; v1 = ov1; i1 = oi1;
  } else {
    if (lexlt(ov1, oi1, v2, i2)) { v2 = ov1; i2 = oi1; }
  }
}

// ---------------- K0: split cb and W into bf16 hi/lo ----------------
__global__ __launch_bounds__(256) void k_cvt2(
    const float* __restrict__ cb, const float* __restrict__ W,
    ushort_t* __restrict__ cbh, ushort_t* __restrict__ cbl,
    ushort_t* __restrict__ wh, ushort_t* __restrict__ wl) {
  const size_t i = ((size_t)blockIdx.x * 256 + threadIdx.x) * 4;
  const size_t CD = (size_t)C * D;
  const float* src; ushort_t* dh; ushort_t* dl; size_t off;
  if (i < CD) { src = cb; dh = cbh; dl = cbl; off = i; }
  else        { src = W;  dh = wh;  dl = wl;  off = i - CD; }
  float4 v = *(const float4*)(src + off);
  ushort4 h, l;
  h.x = f2bf(v.x); l.x = f2bf(v.x - bf2f(h.x));
  h.y = f2bf(v.y); l.y = f2bf(v.y - bf2f(h.y));
  h.z = f2bf(v.z); l.z = f2bf(v.z - bf2f(h.z));
  h.w = f2bf(v.w); l.w = f2bf(v.w - bf2f(h.w));
  *(ushort4*)(dh + off) = h;
  *(ushort4*)(dl + off) = l;
}

// ---------------- K1: implicit = cb @ W^T via 3-leg split-bf16 MFMA ----------------
__global__ __launch_bounds__(256, 2) void k_implicit(
    const ushort_t* __restrict__ cbh, const ushort_t* __restrict__ cbl,
    const ushort_t* __restrict__ wh, const ushort_t* __restrict__ wl,
    float* __restrict__ imp, float* __restrict__ qnorm2,
    ushort_t* __restrict__ ih) {
  __shared__ ushort_t Ah[128 * 32], Al[128 * 32], Bh[128 * 32], Bl[128 * 32];
  const int c0 = blockIdx.x * 128;
  const int j0 = blockIdx.y * 128;
  const int t = threadIdx.x;
  const int wid = t >> 6, lane = t & 63;
  const int wr = wid >> 1, wc = wid & 1;

  const int srow = t >> 2;
  const int koff = (((t & 3) ^ ((t >> 3) & 3)) << 3);

  f32x4 acc[4][4];
#pragma unroll
  for (int m = 0; m < 4; ++m)
#pragma unroll
    for (int n = 0; n < 4; ++n) acc[m][n] = (f32x4){0.f, 0.f, 0.f, 0.f};

  char* lAh = (char*)Ah + wid * 1024;
  char* lAl = (char*)Al + wid * 1024;
  char* lBh = (char*)Bh + wid * 1024;
  char* lBl = (char*)Bl + wid * 1024;

  const int arow = wr * 64 + (lane & 15);
  const int brow = wc * 64 + (lane & 15);
  const int swz = (((lane >> 4) ^ ((lane >> 1) & 3)) << 3);

  const size_t gA0 = (size_t)(c0 + srow) * D + koff;
  const size_t gB0 = (size_t)(j0 + srow) * D + koff;

  for (int kk = 0; kk < D; kk += 32) {
    __syncthreads();
    gld16(lAh,        cbh + gA0 + kk);
    gld16(lAh + 4096, cbh + gA0 + kk + (size_t)64 * D);
    gld16(lAl,        cbl + gA0 + kk);
    gld16(lAl + 4096, cbl + gA0 + kk + (size_t)64 * D);
    gld16(lBh,        wh + gB0 + kk);
    gld16(lBh + 4096, wh + gB0 + kk + (size_t)64 * D);
    gld16(lBl,        wl + gB0 + kk);
    gld16(lBl + 4096, wl + gB0 + kk + (size_t)64 * D);
    __syncthreads();

    bf16x8 ah[4], al4[4], bh[4], bl4[4];
#pragma unroll
    for (int m = 0; m < 4; ++m) {
      ah[m]  = *(const bf16x8*)&Ah[(arow + m * 16) * 32 + swz];
      al4[m] = *(const bf16x8*)&Al[(arow + m * 16) * 32 + swz];
    }
#pragma unroll
    for (int n = 0; n < 4; ++n) {
      bh[n]  = *(const bf16x8*)&Bh[(brow + n * 16) * 32 + swz];
      bl4[n] = *(const bf16x8*)&Bl[(brow + n * 16) * 32 + swz];
    }
#pragma unroll
    for (int m = 0; m < 4; ++m)
#pragma unroll
      for (int n = 0; n < 4; ++n) {
        acc[m][n] = __builtin_amdgcn_mfma_f32_16x16x32_bf16(ah[m],  bh[n],  acc[m][n], 0, 0, 0);
        acc[m][n] = __builtin_amdgcn_mfma_f32_16x16x32_bf16(ah[m],  bl4[n], acc[m][n], 0, 0, 0);
        acc[m][n] = __builtin_amdgcn_mfma_f32_16x16x32_bf16(al4[m], bh[n],  acc[m][n], 0, 0, 0);
      }
  }

#pragma unroll
  for (int m = 0; m < 4; ++m)
#pragma unroll
    for (int r = 0; r < 4; ++r) {
      const int rowg = c0 + wr * 64 + m * 16 + (lane >> 4) * 4 + r;
      float sq = 0.f;
#pragma unroll
      for (int n = 0; n < 4; ++n) {
        const float v = acc[m][n][r];
        const int colg = j0 + wc * 64 + n * 16 + (lane & 15);
        imp[(size_t)rowg * D + colg] = v;
        ih[(size_t)rowg * D + colg] = f2bf(v);
        sq = fmaf(v, v, sq);
      }
#pragma unroll
      for (int mm = 1; mm < 16; mm <<= 1) sq += __shfl_xor(sq, mm, 64);
      if ((lane & 15) == 0) atomicAdd(&qnorm2[rowg], sq);
    }
}

// ---------------- K1b: x -> xh bf16 ----------------
__global__ __launch_bounds__(256) void k_cvt(const float* __restrict__ x,
                                             ushort_t* __restrict__ xh) {
  const size_t i = ((size_t)blockIdx.x * 256 + threadIdx.x) * 4;
  float4 v = *(const float4*)(x + i);
  ushort4 h;
  h.x = f2bf(v.x); h.y = f2bf(v.y); h.z = f2bf(v.z); h.w = f2bf(v.w);
  *(ushort4*)(xh + i) = h;
}

// ---------------- K2: 1-leg MFMA distance + fused TOP-2 argmin ----------------
// grid (64, 16), 512 thr (8 waves: wr=wid>>2 row-half of 128, wn=wid&3
// col-quarter of 64). 256x256 tile, BK=64, SINGLE-buffer 64 KB LDS ->
// 2 blocks/CU resident (the r12 structure minus its occupancy-killing dbuf).
__global__ __launch_bounds__(512) void k_dist(
    const ushort_t* __restrict__ xh, const ushort_t* __restrict__ ih,
    const float* __restrict__ qnorm2,
    float2* __restrict__ t2v, int2* __restrict__ t2i) {
  __shared__ ushort_t Ah[256 * 64], Bh[256 * 64];   // 32 KB each
  const int r0 = blockIdx.x * 256;
  const int c0 = blockIdx.y * 256;
  const int t = threadIdx.x;
  const int wid = t >> 6, lane = t & 63;
  const int wr = wid >> 2;            // 0..1: row half (128 rows)
  const int wn = wid & 3;             // 0..3: col quarter (64 cols)

  // staging: thread t -> rows (t>>3)+64j (j=0..3), phys chunk t&7.
  // source pre-swizzled: chunk_log = (t&7) ^ ((t>>3)&7)  (row&7 == (t>>3)&7)
  const int koff = (((t & 7) ^ ((t >> 3) & 7)) << 3);   // elems
  const size_t gA0 = (size_t)(r0 + (t >> 3)) * D + koff;
  const size_t gB0 = (size_t)(c0 + (t >> 3)) * D + koff;
  char* lA = (char*)Ah + wid * 1024;   // wave-linear dest; j-block stride 8 KB
  char* lB = (char*)Bh + wid * 1024;

  f32x4 acc[8][4];
#pragma unroll
  for (int m = 0; m < 8; ++m)
#pragma unroll
    for (int n = 0; n < 4; ++n) acc[m][n] = (f32x4){0.f, 0.f, 0.f, 0.f};

  // fragment reads: row = base16 + (lane&15), row&7 = lane&7.
  // log chunk = (lane>>4) + 4*ks ; phys = log ^ (lane&7)
  const int arow = wr * 128 + (lane & 15);
  const int brow = wn * 64 + (lane & 15);

  for (int kk = 0; kk < D; kk += 64) {
    __syncthreads();
#pragma unroll
    for (int j = 0; j < 4; ++j) {
      gld16(lA + j * 8192, xh + gA0 + kk + (size_t)(64 * j) * D);
      gld16(lB + j * 8192, ih + gB0 + kk + (size_t)(64 * j) * D);
    }
    __syncthreads();   // drains vmcnt(0) -> tiles ready

#pragma unroll
    for (int ks = 0; ks < 2; ++ks) {
      const int cpx = ((((lane >> 4) + 4 * ks) ^ (lane & 7)) << 4);
      bf16x8 a[8], b[4];
#pragma unroll
      for (int m = 0; m < 8; ++m)
        a[m] = *(const bf16x8*)((const char*)Ah + ((arow + m * 16) << 7) + cpx);
#pragma unroll
      for (int n = 0; n < 4; ++n)
        b[n] = *(const bf16x8*)((const char*)Bh + ((brow + n * 16) << 7) + cpx);
#pragma unroll
      for (int m = 0; m < 8; ++m)
#pragma unroll
        for (int n = 0; n < 4; ++n)
          acc[m][n] = __builtin_amdgcn_mfma_f32_16x16x32_bf16(a[m], b[n], acc[m][n], 0, 0, 0);
    }
  }

  // epilogue: score = qn[c] - 2*dot ; per-row TOP-2 over THIS WAVE's 64 cols.
  // Unique writer per (row, slice): slice = by*4 + wn; t2 row-major [row][64].
  int colg[4]; float qnv[4];
#pragma unroll
  for (int n = 0; n < 4; ++n) {
    colg[n] = c0 + wn * 64 + n * 16 + (lane & 15);
    qnv[n] = qnorm2[colg[n]];
  }
  const int sp2 = blockIdx.y * 4 + wn;
#pragma unroll
  for (int m = 0; m < 8; ++m)
#pragma unroll
    for (int r = 0; r < 4; ++r) {
      float v1 = fmaf(-2.f, acc[m][0][r], qnv[0]); int i1 = colg[0];
      float v2 = 3.4e38f;                          int i2 = 0x7fffffff;
#pragma unroll
      for (int n = 1; n < 4; ++n) {
        const float s = fmaf(-2.f, acc[m][n][r], qnv[n]);
        const int   c = colg[n];
        if (lexlt(s, c, v1, i1)) { v2 = v1; i2 = i1; v1 = s; i1 = c; }
        else if (lexlt(s, c, v2, i2)) { v2 = s; i2 = c; }
      }
#pragma unroll
      for (int off = 1; off < 16; off <<= 1) {
        const float ov1 = __shfl_xor(v1, off, 64);
        const int   oi1 = __shfl_xor(i1, off, 64);
        const float ov2 = __shfl_xor(v2, off, 64);
        const int   oi2 = __shfl_xor(i2, off, 64);
        top2_merge(v1, i1, v2, i2, ov1, oi1, ov2, oi2);
      }
      if ((lane & 15) == 0) {
        const int row = r0 + wr * 128 + m * 16 + (lane >> 4) * 4 + r;
        t2v[(size_t)row * NSL + sp2] = make_float2(v1, v2);
        t2i[(size_t)row * NSL + sp2] = make_int2(i1, i2);
      }
    }
}

// compare-exchange ascending (lex) on named scalars
#define CE(vx, ix, vy, iy)                                        \
  do {                                                            \
    if (lexlt(vy, iy, vx, ix)) {                                  \
      float tv = vx; int ti = ix;                                 \
      vx = vy; ix = iy; vy = tv; iy = ti;                         \
    }                                                             \
  } while (0)

// ---------------- K3: wave-per-row top-4 merge + fp64 rescore + rotation ----------------
__global__ __launch_bounds__(256) void k_rot(
    const float* __restrict__ x, const float* __restrict__ imp,
    const float2* __restrict__ t2v, const int2* __restrict__ t2i,
    float* __restrict__ out, float* __restrict__ commit_acc) {
  const int tid = threadIdx.x;
  const int wid = tid >> 6, lane = tid & 63;
  const int row = blockIdx.x * 4 + wid;

  const float2 vv = t2v[(size_t)row * NSL + lane];
  const int2   ii = t2i[(size_t)row * NSL + lane];
  float a0 = vv.x, a1 = vv.y, a2 = 3.4e38f, a3 = 3.4e38f;
  int   j0 = ii.x, j1 = ii.y, j2 = 0x7fffffff, j3 = 0x7fffffff;
#pragma unroll
  for (int off = 1; off < 64; off <<= 1) {
    const float b0 = __shfl_xor(a0, off, 64), b1 = __shfl_xor(a1, off, 64);
    const float b2 = __shfl_xor(a2, off, 64), b3 = __shfl_xor(a3, off, 64);
    const int   k0 = __shfl_xor(j0, off, 64), k1 = __shfl_xor(j1, off, 64);
    const int   k2 = __shfl_xor(j2, off, 64), k3 = __shfl_xor(j3, off, 64);
    float m0 = a0, m1 = a1, m2 = a2, m3 = a3;
    int   n0 = j0, n1 = j1, n2 = j2, n3 = j3;
    if (lexlt(b3, k3, m0, n0)) { m0 = b3; n0 = k3; }
    if (lexlt(b2, k2, m1, n1)) { m1 = b2; n1 = k2; }
    if (lexlt(b1, k1, m2, n2)) { m2 = b1; n2 = k1; }
    if (lexlt(b0, k0, m3, n3)) { m3 = b0; n3 = k0; }
    CE(m0, n0, m2, n2); CE(m1, n1, m3, n3);
    CE(m0, n0, m1, n1); CE(m2, n2, m3, n3);
    a0 = m0; a1 = m1; a2 = m2; a3 = m3;
    j0 = n0; j1 = n1; j2 = n2; j3 = n3;
  }
  const bool need = (a1 - a0 < DELTA);

  const float* xr = x + (size_t)row * D + lane * 8;
  const float4 xa = *(const float4*)(xr);
  const float4 xb = *(const float4*)(xr + 4);
  const float xs[8] = {xa.x, xa.y, xa.z, xa.w, xb.x, xb.y, xb.z, xb.w};

  int bi = j0;
  if (need) {
    double s0 = 0.0, s1 = 0.0, s2 = 0.0, s3 = 0.0;
    {
      const float* q0 = imp + (size_t)j0 * D + lane * 8;
      const float* q1 = imp + (size_t)j1 * D + lane * 8;
      const float* q2 = imp + (size_t)j2 * D + lane * 8;
      const float* q3 = imp + (size_t)j3 * D + lane * 8;
      const float4 q0a = *(const float4*)(q0), q0b = *(const float4*)(q0 + 4);
      const float4 q1a = *(const float4*)(q1), q1b = *(const float4*)(q1 + 4);
      const float4 q2a = *(const float4*)(q2), q2b = *(const float4*)(q2 + 4);
      const float4 q3a = *(const float4*)(q3), q3b = *(const float4*)(q3 + 4);
      const float q0s[8] = {q0a.x, q0a.y, q0a.z, q0a.w, q0b.x, q0b.y, q0b.z, q0b.w};
      const float q1s[8] = {q1a.x, q1a.y, q1a.z, q1a.w, q1b.x, q1b.y, q1b.z, q1b.w};
      const float q2s[8] = {q2a.x, q2a.y, q2a.z, q2a.w, q2b.x, q2b.y, q2b.z, q2b.w};
      const float q3s[8] = {q3a.x, q3a.y, q3a.z, q3a.w, q3b.x, q3b.y, q3b.z, q3b.w};
#pragma unroll
      for (int e = 0; e < 8; ++e) {
        const double xe = (double)xs[e];
        double d;
        d = xe - (double)q0s[e]; s0 += d * d;
        d = xe - (double)q1s[e]; s1 += d * d;
        d = xe - (double)q2s[e]; s2 += d * d;
        d = xe - (double)q3s[e]; s3 += d * d;
      }
    }
#pragma unroll
    for (int m = 1; m < 64; m <<= 1) {
      s0 += __shfl_xor(s0, m, 64);
      s1 += __shfl_xor(s1, m, 64);
      s2 += __shfl_xor(s2, m, 64);
      s3 += __shfl_xor(s3, m, 64);
    }
    double bd = s0; bi = j0;
    if (s1 < bd || (s1 == bd && j1 < bi)) { bd = s1; bi = j1; }
    if (s2 < bd || (s2 == bd && j2 < bi)) { bd = s2; bi = j2; }
    if (s3 < bd || (s3 == bd && j3 < bi)) { bd = s3; bi = j3; }
  }

  const float* qr = imp + (size_t)bi * D + lane * 8;
  const float4 qa4 = *(const float4*)(qr);
  const float4 qb4 = *(const float4*)(qr + 4);
  const float qs[8] = {qa4.x, qa4.y, qa4.z, qa4.w, qb4.x, qb4.y, qb4.z, qb4.w};

  float sx2 = 0.f, sq2 = 0.f, sxq = 0.f, scm = 0.f;
#pragma unroll
  for (int e = 0; e < 8; ++e) {
    sx2 = fmaf(xs[e], xs[e], sx2);
    sq2 = fmaf(qs[e], qs[e], sq2);
    sxq = fmaf(xs[e], qs[e], sxq);
    const float de = xs[e] - qs[e] + 1e-6f;
    scm = fmaf(de, de, scm);
  }
#pragma unroll
  for (int m = 1; m < 64; m <<= 1) {
    sx2 += __shfl_xor(sx2, m, 64);
    sq2 += __shfl_xor(sq2, m, 64);
    sxq += __shfl_xor(sxq, m, 64);
    scm += __shfl_xor(scm, m, 64);
  }

  const float norm_x = sqrtf(sx2), norm_q = sqrtf(sq2);
  const float cnx = fmaxf(norm_x, 1e-6f), cnq = fmaxf(norm_q, 1e-6f);
  const float inx = 1.0f / cnx, inq = 1.0f / cnq;
  const float nuq2 = sx2 * inx * inx + 2.0f * sxq * inx * inq + sq2 * inq * inq;
  const float iw = 1.0f / fmaxf(sqrtf(nuq2), 1e-12f);
  const float e_dot_u = sx2 * inx;
  const float e_dot_w = (sx2 * inx + sxq * inq) * iw;
  const float scale = norm_q * inx;

  float os[8];
#pragma unroll
  for (int e = 0; e < 8; ++e) {
    const float we = (xs[e] * inx + qs[e] * inq) * iw;
    float re = xs[e] - 2.0f * e_dot_w * we;
    re = fmaf(2.0f * e_dot_u, qs[e] * inq, re);
    os[e] = re * scale;
  }
  float* op = out + (size_t)row * D + lane * 8;
  *(float4*)(op)     = make_float4(os[0], os[1], os[2], os[3]);
  *(float4*)(op + 4) = make_float4(os[4], os[5], os[6], os[7]);

  if (lane == 0) {
    atomicAdd(commit_acc, scm);
    out[(size_t)NR * D + row] = (float)bi;
  }
}
#undef CE

// ---------------- K4: finalize commit loss ----------------
__global__ void k_final(const float* __restrict__ commit_acc,
                        float* __restrict__ out) {
  out[(size_t)NR * D + NR] = *commit_acc * (1.0f / (float)NR);
}

extern "C" void kernel_launch(void* const* d_in, const int* in_sizes, int n_in,
                              void* d_out, int out_size, void* d_ws, size_t ws_size,
                              hipStream_t stream) {
  const float* x  = (const float*)d_in[0];
  const float* cb = (const float*)d_in[1];
  const float* W  = (const float*)d_in[2];
  float* out = (float*)d_out;

  float* ws     = (float*)d_ws;
  float*  imp    = ws;                                   // C*D f32      (8 MB)
  float*  qnorm2 = imp + (size_t)C * D;                  // C
  float2* t2v    = (float2*)(qnorm2 + C);                // NR*NSL       (8 MB)
  int2*   t2i    = (int2*)(t2v + (size_t)NR * NSL);      // NR*NSL       (8 MB)
  float*  commit = (float*)(t2i + (size_t)NR * NSL);     // 4
  ushort_t* ih   = (ushort_t*)(commit + 4);              // C*D bf16     (4 MB)
  ushort_t* cbh  = ih + (size_t)C * D;                   // C*D bf16     (4 MB)
  ushort_t* cbl  = cbh + (size_t)C * D;                  // C*D bf16     (4 MB)
  ushort_t* wh   = cbl + (size_t)C * D;                  // D*D bf16
  ushort_t* wl   = wh + (size_t)D * D;                   // D*D bf16

  // xh scratch in d_out's quantized region (16 MB), overwritten by k_rot
  ushort_t* xh = (ushort_t*)out;                         // NR*D bf16

  hipMemsetAsync(qnorm2, 0, C * sizeof(float), stream);
  hipMemsetAsync(commit, 0, 4 * sizeof(float), stream);

  k_cvt2<<<((C + D) * D) / (256 * 4), 256, 0, stream>>>(cb, W, cbh, cbl, wh, wl);
  k_implicit<<<dim3(C / 128, D / 128), 256, 0, stream>>>(cbh, cbl, wh, wl, imp, qnorm2, ih);
  k_cvt<<<(NR * D) / (256 * 4), 256, 0, stream>>>(x, xh);
  k_dist<<<dim3(64, 16), 512, 0, stream>>>(xh, ih, qnorm2, t2v, t2i);
  k_rot<<<NR / 4, 256, 0, stream>>>(x, imp, t2v, t2i, out, commit);
  k_final<<<1, 1, 0, stream>>>(commit, out);
}

// Round 18
// 558.264 us; speedup vs baseline: 1.0471x; 1.0471x over previous
//
#include <hip/hip_runtime.h>
#include <hip/hip_bf16.h>

// SimVQ: x[8,2048,512] f32, codebook[4096,512] f32, W[512,512] f32
// out (f32 flat): quantized_out[16384*512] | indices[16384] (as f32) | commit_loss[1]
//
// Round 18: revert to round-16 verbatim (measured best: 558.5 us).
// r17's 256^2 single-buffer was register-capped to 1 block/CU (216 regs/lane)
// and regressed per the residency law; r13-structure k_dist at R~3.4 is the
// family optimum. This round re-validates the best known configuration.

typedef unsigned short ushort_t;
typedef __attribute__((ext_vector_type(8))) short bf16x8;
typedef __attribute__((ext_vector_type(4))) float f32x4;

constexpr int D  = 512;
constexpr int C  = 4096;
constexpr int NR = 16384;
constexpr int NSL = 64;             // partial slices per row (row-major)
constexpr float DELTA = 1.0f;       // top-4 fp64 rescue threshold

__device__ __forceinline__ ushort_t f2bf(float v) {
  __hip_bfloat16 h = __float2bfloat16(v);
  return *reinterpret_cast<ushort_t*>(&h);
}
__device__ __forceinline__ float bf2f(ushort_t u) {
  __hip_bfloat16 h;
  *reinterpret_cast<ushort_t*>(&h) = u;
  return __bfloat162float(h);
}

__device__ __forceinline__ void gld16(void* lds, const void* g) {
  __builtin_amdgcn_global_load_lds(
      (const __attribute__((address_space(1))) unsigned int*)g,
      (__attribute__((address_space(3))) unsigned int*)lds, 16, 0, 0);
}

__device__ __forceinline__ bool lexlt(float v, int i, float ov, int oi) {
  return v < ov || (v == ov && i < oi);
}

__device__ __forceinline__ void top2_merge(float& v1, int& i1, float& v2, int& i2,
                                           float ov1, int oi1, float ov2, int oi2) {
  if (lexlt(ov1, oi1, v1, i1)) {
    float nv2; int ni2;
    if (lexlt(v1, i1, ov2, oi2)) { nv2 = v1; ni2 = i1; }
    else { nv2 = ov2; ni2 = oi2; }
    v2 = nv2; i2 = ni2; v1 = ov1; i1 = oi1;
  } else {
    if (lexlt(ov1, oi1, v2, i2)) { v2 = ov1; i2 = oi1; }
  }
}

// ---------------- K0: split cb and W into bf16 hi/lo ----------------
__global__ __launch_bounds__(256) void k_cvt2(
    const float* __restrict__ cb, const float* __restrict__ W,
    ushort_t* __restrict__ cbh, ushort_t* __restrict__ cbl,
    ushort_t* __restrict__ wh, ushort_t* __restrict__ wl) {
  const size_t i = ((size_t)blockIdx.x * 256 + threadIdx.x) * 4;
  const size_t CD = (size_t)C * D;
  const float* src; ushort_t* dh; ushort_t* dl; size_t off;
  if (i < CD) { src = cb; dh = cbh; dl = cbl; off = i; }
  else        { src = W;  dh = wh;  dl = wl;  off = i - CD; }
  float4 v = *(const float4*)(src + off);
  ushort4 h, l;
  h.x = f2bf(v.x); l.x = f2bf(v.x - bf2f(h.x));
  h.y = f2bf(v.y); l.y = f2bf(v.y - bf2f(h.y));
  h.z = f2bf(v.z); l.z = f2bf(v.z - bf2f(h.z));
  h.w = f2bf(v.w); l.w = f2bf(v.w - bf2f(h.w));
  *(ushort4*)(dh + off) = h;
  *(ushort4*)(dl + off) = l;
}

// ---------------- K1: implicit = cb @ W^T via 3-leg split-bf16 MFMA ----------------
__global__ __launch_bounds__(256, 2) void k_implicit(
    const ushort_t* __restrict__ cbh, const ushort_t* __restrict__ cbl,
    const ushort_t* __restrict__ wh, const ushort_t* __restrict__ wl,
    float* __restrict__ imp, float* __restrict__ qnorm2,
    ushort_t* __restrict__ ih) {
  __shared__ ushort_t Ah[128 * 32], Al[128 * 32], Bh[128 * 32], Bl[128 * 32];
  const int c0 = blockIdx.x * 128;
  const int j0 = blockIdx.y * 128;
  const int t = threadIdx.x;
  const int wid = t >> 6, lane = t & 63;
  const int wr = wid >> 1, wc = wid & 1;

  const int srow = t >> 2;
  const int koff = (((t & 3) ^ ((t >> 3) & 3)) << 3);

  f32x4 acc[4][4];
#pragma unroll
  for (int m = 0; m < 4; ++m)
#pragma unroll
    for (int n = 0; n < 4; ++n) acc[m][n] = (f32x4){0.f, 0.f, 0.f, 0.f};

  char* lAh = (char*)Ah + wid * 1024;
  char* lAl = (char*)Al + wid * 1024;
  char* lBh = (char*)Bh + wid * 1024;
  char* lBl = (char*)Bl + wid * 1024;

  const int arow = wr * 64 + (lane & 15);
  const int brow = wc * 64 + (lane & 15);
  const int swz = (((lane >> 4) ^ ((lane >> 1) & 3)) << 3);

  const size_t gA0 = (size_t)(c0 + srow) * D + koff;
  const size_t gB0 = (size_t)(j0 + srow) * D + koff;

  for (int kk = 0; kk < D; kk += 32) {
    __syncthreads();
    gld16(lAh,        cbh + gA0 + kk);
    gld16(lAh + 4096, cbh + gA0 + kk + (size_t)64 * D);
    gld16(lAl,        cbl + gA0 + kk);
    gld16(lAl + 4096, cbl + gA0 + kk + (size_t)64 * D);
    gld16(lBh,        wh + gB0 + kk);
    gld16(lBh + 4096, wh + gB0 + kk + (size_t)64 * D);
    gld16(lBl,        wl + gB0 + kk);
    gld16(lBl + 4096, wl + gB0 + kk + (size_t)64 * D);
    __syncthreads();

    bf16x8 ah[4], al4[4], bh[4], bl4[4];
#pragma unroll
    for (int m = 0; m < 4; ++m) {
      ah[m]  = *(const bf16x8*)&Ah[(arow + m * 16) * 32 + swz];
      al4[m] = *(const bf16x8*)&Al[(arow + m * 16) * 32 + swz];
    }
#pragma unroll
    for (int n = 0; n < 4; ++n) {
      bh[n]  = *(const bf16x8*)&Bh[(brow + n * 16) * 32 + swz];
      bl4[n] = *(const bf16x8*)&Bl[(brow + n * 16) * 32 + swz];
    }
#pragma unroll
    for (int m = 0; m < 4; ++m)
#pragma unroll
      for (int n = 0; n < 4; ++n) {
        acc[m][n] = __builtin_amdgcn_mfma_f32_16x16x32_bf16(ah[m],  bh[n],  acc[m][n], 0, 0, 0);
        acc[m][n] = __builtin_amdgcn_mfma_f32_16x16x32_bf16(ah[m],  bl4[n], acc[m][n], 0, 0, 0);
        acc[m][n] = __builtin_amdgcn_mfma_f32_16x16x32_bf16(al4[m], bh[n],  acc[m][n], 0, 0, 0);
      }
  }

#pragma unroll
  for (int m = 0; m < 4; ++m)
#pragma unroll
    for (int r = 0; r < 4; ++r) {
      const int rowg = c0 + wr * 64 + m * 16 + (lane >> 4) * 4 + r;
      float sq = 0.f;
#pragma unroll
      for (int n = 0; n < 4; ++n) {
        const float v = acc[m][n][r];
        const int colg = j0 + wc * 64 + n * 16 + (lane & 15);
        imp[(size_t)rowg * D + colg] = v;
        ih[(size_t)rowg * D + colg] = f2bf(v);
        sq = fmaf(v, v, sq);
      }
#pragma unroll
      for (int mm = 1; mm < 16; mm <<= 1) sq += __shfl_xor(sq, mm, 64);
      if ((lane & 15) == 0) atomicAdd(&qnorm2[rowg], sq);
    }
}

// ---------------- K1b: x -> xh bf16 ----------------
__global__ __launch_bounds__(256) void k_cvt(const float* __restrict__ x,
                                             ushort_t* __restrict__ xh) {
  const size_t i = ((size_t)blockIdx.x * 256 + threadIdx.x) * 4;
  float4 v = *(const float4*)(x + i);
  ushort4 h;
  h.x = f2bf(v.x); h.y = f2bf(v.y); h.z = f2bf(v.z); h.w = f2bf(v.w);
  *(ushort4*)(xh + i) = h;
}

// ---------------- K2: 1-leg MFMA distance + fused TOP-2 argmin (round-13) ----------------
__global__ __launch_bounds__(256, 4) void k_dist(
    const ushort_t* __restrict__ xh, const ushort_t* __restrict__ ih,
    const float* __restrict__ qnorm2,
    float2* __restrict__ t2v, int2* __restrict__ t2i) {
  __shared__ ushort_t Ah[128 * 64], Bh[128 * 64];   // 16 KB each
  const int id = blockIdx.x;
  const int bx = ((id >> 8) << 3) + (id & 7);
  const int by = (id >> 3) & 31;
  const int r0 = bx * 128;
  const int c0 = by * 128;
  const int t = threadIdx.x;
  const int wid = t >> 6, lane = t & 63;
  const int wr = wid >> 1, wc = wid & 1;

  const int koff = (((t & 7) ^ ((t >> 3) & 7)) << 3);   // elems
  const size_t gA0 = (size_t)(r0 + (t >> 3)) * D + koff;
  const size_t gB0 = (size_t)(c0 + (t >> 3)) * D + koff;
  char* lA = (char*)Ah + wid * 1024;
  char* lB = (char*)Bh + wid * 1024;

  f32x4 acc[4][4];
#pragma unroll
  for (int m = 0; m < 4; ++m)
#pragma unroll
    for (int n = 0; n < 4; ++n) acc[m][n] = (f32x4){0.f, 0.f, 0.f, 0.f};

  const int arow = wr * 64 + (lane & 15);
  const int brow = wc * 64 + (lane & 15);
  const int cp0 = (((lane >> 4) ^ (lane & 7)) << 4);    // bytes

  for (int kk = 0; kk < D; kk += 64) {
    __syncthreads();
#pragma unroll
    for (int j = 0; j < 4; ++j) {
      gld16(lA + j * 4096, xh + gA0 + kk + (size_t)(32 * j) * D);
      gld16(lB + j * 4096, ih + gB0 + kk + (size_t)(32 * j) * D);
    }
    __syncthreads();

#pragma unroll
    for (int ks = 0; ks < 2; ++ks) {
      const int kx = cp0 ^ (ks << 6);
      bf16x8 a[4], b[4];
#pragma unroll
      for (int m = 0; m < 4; ++m)
        a[m] = *(const bf16x8*)((const char*)Ah + ((arow + m * 16) << 7) + kx);
#pragma unroll
      for (int n = 0; n < 4; ++n)
        b[n] = *(const bf16x8*)((const char*)Bh + ((brow + n * 16) << 7) + kx);
#pragma unroll
      for (int m = 0; m < 4; ++m)
#pragma unroll
        for (int n = 0; n < 4; ++n)
          acc[m][n] = __builtin_amdgcn_mfma_f32_16x16x32_bf16(a[m], b[n], acc[m][n], 0, 0, 0);
    }
  }

  int colg[4]; float qnv[4];
#pragma unroll
  for (int n = 0; n < 4; ++n) {
    colg[n] = c0 + wc * 64 + n * 16 + (lane & 15);
    qnv[n] = qnorm2[colg[n]];
  }
  const int sp2 = by * 2 + wc;
#pragma unroll
  for (int m = 0; m < 4; ++m)
#pragma unroll
    for (int r = 0; r < 4; ++r) {
      float v1 = fmaf(-2.f, acc[m][0][r], qnv[0]); int i1 = colg[0];
      float v2 = 3.4e38f;                          int i2 = 0x7fffffff;
#pragma unroll
      for (int n = 1; n < 4; ++n) {
        const float s = fmaf(-2.f, acc[m][n][r], qnv[n]);
        const int   c = colg[n];
        if (lexlt(s, c, v1, i1)) { v2 = v1; i2 = i1; v1 = s; i1 = c; }
        else if (lexlt(s, c, v2, i2)) { v2 = s; i2 = c; }
      }
#pragma unroll
      for (int off = 1; off < 16; off <<= 1) {
        const float ov1 = __shfl_xor(v1, off, 64);
        const int   oi1 = __shfl_xor(i1, off, 64);
        const float ov2 = __shfl_xor(v2, off, 64);
        const int   oi2 = __shfl_xor(i2, off, 64);
        top2_merge(v1, i1, v2, i2, ov1, oi1, ov2, oi2);
      }
      if ((lane & 15) == 0) {
        const int row = r0 + wr * 64 + m * 16 + (lane >> 4) * 4 + r;
        t2v[(size_t)row * NSL + sp2] = make_float2(v1, v2);
        t2i[(size_t)row * NSL + sp2] = make_int2(i1, i2);
      }
    }
}

// compare-exchange ascending (lex) on named scalars
#define CE(vx, ix, vy, iy)                                        \
  do {                                                            \
    if (lexlt(vy, iy, vx, ix)) {                                  \
      float tv = vx; int ti = ix;                                 \
      vx = vy; ix = iy; vy = tv; iy = ti;                         \
    }                                                             \
  } while (0)

// ---------------- K3: wave-per-row top-4 merge + fp64 rescore + rotation ----------------
__global__ __launch_bounds__(256) void k_rot(
    const float* __restrict__ x, const float* __restrict__ imp,
    const float2* __restrict__ t2v, const int2* __restrict__ t2i,
    float* __restrict__ out, float* __restrict__ commit_acc) {
  const int tid = threadIdx.x;
  const int wid = tid >> 6, lane = tid & 63;
  const int row = blockIdx.x * 4 + wid;

  const float2 vv = t2v[(size_t)row * NSL + lane];
  const int2   ii = t2i[(size_t)row * NSL + lane];
  float a0 = vv.x, a1 = vv.y, a2 = 3.4e38f, a3 = 3.4e38f;
  int   j0 = ii.x, j1 = ii.y, j2 = 0x7fffffff, j3 = 0x7fffffff;
#pragma unroll
  for (int off = 1; off < 64; off <<= 1) {
    const float b0 = __shfl_xor(a0, off, 64), b1 = __shfl_xor(a1, off, 64);
    const float b2 = __shfl_xor(a2, off, 64), b3 = __shfl_xor(a3, off, 64);
    const int   k0 = __shfl_xor(j0, off, 64), k1 = __shfl_xor(j1, off, 64);
    const int   k2 = __shfl_xor(j2, off, 64), k3 = __shfl_xor(j3, off, 64);
    float m0 = a0, m1 = a1, m2 = a2, m3 = a3;
    int   n0 = j0, n1 = j1, n2 = j2, n3 = j3;
    if (lexlt(b3, k3, m0, n0)) { m0 = b3; n0 = k3; }
    if (lexlt(b2, k2, m1, n1)) { m1 = b2; n1 = k2; }
    if (lexlt(b1, k1, m2, n2)) { m2 = b1; n2 = k1; }
    if (lexlt(b0, k0, m3, n3)) { m3 = b0; n3 = k0; }
    CE(m0, n0, m2, n2); CE(m1, n1, m3, n3);
    CE(m0, n0, m1, n1); CE(m2, n2, m3, n3);
    a0 = m0; a1 = m1; a2 = m2; a3 = m3;
    j0 = n0; j1 = n1; j2 = n2; j3 = n3;
  }
  const bool need = (a1 - a0 < DELTA);

  const float* xr = x + (size_t)row * D + lane * 8;
  const float4 xa = *(const float4*)(xr);
  const float4 xb = *(const float4*)(xr + 4);
  const float xs[8] = {xa.x, xa.y, xa.z, xa.w, xb.x, xb.y, xb.z, xb.w};

  int bi = j0;
  if (need) {
    double s0 = 0.0, s1 = 0.0, s2 = 0.0, s3 = 0.0;
    {
      const float* q0 = imp + (size_t)j0 * D + lane * 8;
      const float* q1 = imp + (size_t)j1 * D + lane * 8;
      const float* q2 = imp + (size_t)j2 * D + lane * 8;
      const float* q3 = imp + (size_t)j3 * D + lane * 8;
      const float4 q0a = *(const float4*)(q0), q0b = *(const float4*)(q0 + 4);
      const float4 q1a = *(const float4*)(q1), q1b = *(const float4*)(q1 + 4);
      const float4 q2a = *(const float4*)(q2), q2b = *(const float4*)(q2 + 4);
      const float4 q3a = *(const float4*)(q3), q3b = *(const float4*)(q3 + 4);
      const float q0s[8] = {q0a.x, q0a.y, q0a.z, q0a.w, q0b.x, q0b.y, q0b.z, q0b.w};
      const float q1s[8] = {q1a.x, q1a.y, q1a.z, q1a.w, q1b.x, q1b.y, q1b.z, q1b.w};
      const float q2s[8] = {q2a.x, q2a.y, q2a.z, q2a.w, q2b.x, q2b.y, q2b.z, q2b.w};
      const float q3s[8] = {q3a.x, q3a.y, q3a.z, q3a.w, q3b.x, q3b.y, q3b.z, q3b.w};
#pragma unroll
      for (int e = 0; e < 8; ++e) {
        const double xe = (double)xs[e];
        double d;
        d = xe - (double)q0s[e]; s0 += d * d;
        d = xe - (double)q1s[e]; s1 += d * d;
        d = xe - (double)q2s[e]; s2 += d * d;
        d = xe - (double)q3s[e]; s3 += d * d;
      }
    }
#pragma unroll
    for (int m = 1; m < 64; m <<= 1) {
      s0 += __shfl_xor(s0, m, 64);
      s1 += __shfl_xor(s1, m, 64);
      s2 += __shfl_xor(s2, m, 64);
      s3 += __shfl_xor(s3, m, 64);
    }
    double bd = s0; bi = j0;
    if (s1 < bd || (s1 == bd && j1 < bi)) { bd = s1; bi = j1; }
    if (s2 < bd || (s2 == bd && j2 < bi)) { bd = s2; bi = j2; }
    if (s3 < bd || (s3 == bd && j3 < bi)) { bd = s3; bi = j3; }
  }

  const float* qr = imp + (size_t)bi * D + lane * 8;
  const float4 qa4 = *(const float4*)(qr);
  const float4 qb4 = *(const float4*)(qr + 4);
  const float qs[8] = {qa4.x, qa4.y, qa4.z, qa4.w, qb4.x, qb4.y, qb4.z, qb4.w};

  float sx2 = 0.f, sq2 = 0.f, sxq = 0.f, scm = 0.f;
#pragma unroll
  for (int e = 0; e < 8; ++e) {
    sx2 = fmaf(xs[e], xs[e], sx2);
    sq2 = fmaf(qs[e], qs[e], sq2);
    sxq = fmaf(xs[e], qs[e], sxq);
    const float de = xs[e] - qs[e] + 1e-6f;
    scm = fmaf(de, de, scm);
  }
#pragma unroll
  for (int m = 1; m < 64; m <<= 1) {
    sx2 += __shfl_xor(sx2, m, 64);
    sq2 += __shfl_xor(sq2, m, 64);
    sxq += __shfl_xor(sxq, m, 64);
    scm += __shfl_xor(scm, m, 64);
  }

  const float norm_x = sqrtf(sx2), norm_q = sqrtf(sq2);
  const float cnx = fmaxf(norm_x, 1e-6f), cnq = fmaxf(norm_q, 1e-6f);
  const float inx = 1.0f / cnx, inq = 1.0f / cnq;
  const float nuq2 = sx2 * inx * inx + 2.0f * sxq * inx * inq + sq2 * inq * inq;
  const float iw = 1.0f / fmaxf(sqrtf(nuq2), 1e-12f);
  const float e_dot_u = sx2 * inx;
  const float e_dot_w = (sx2 * inx + sxq * inq) * iw;
  const float scale = norm_q * inx;

  float os[8];
#pragma unroll
  for (int e = 0; e < 8; ++e) {
    const float we = (xs[e] * inx + qs[e] * inq) * iw;
    float re = xs[e] - 2.0f * e_dot_w * we;
    re = fmaf(2.0f * e_dot_u, qs[e] * inq, re);
    os[e] = re * scale;
  }
  float* op = out + (size_t)row * D + lane * 8;
  *(float4*)(op)     = make_float4(os[0], os[1], os[2], os[3]);
  *(float4*)(op + 4) = make_float4(os[4], os[5], os[6], os[7]);

  if (lane == 0) {
    atomicAdd(commit_acc, scm);
    out[(size_t)NR * D + row] = (float)bi;
  }
}
#undef CE

// ---------------- K4: finalize commit loss ----------------
__global__ void k_final(const float* __restrict__ commit_acc,
                        float* __restrict__ out) {
  out[(size_t)NR * D + NR] = *commit_acc * (1.0f / (float)NR);
}

extern "C" void kernel_launch(void* const* d_in, const int* in_sizes, int n_in,
                              void* d_out, int out_size, void* d_ws, size_t ws_size,
                              hipStream_t stream) {
  const float* x  = (const float*)d_in[0];
  const float* cb = (const float*)d_in[1];
  const float* W  = (const float*)d_in[2];
  float* out = (float*)d_out;

  float* ws     = (float*)d_ws;
  float*  imp    = ws;                                   // C*D f32      (8 MB)
  float*  qnorm2 = imp + (size_t)C * D;                  // C
  float2* t2v    = (float2*)(qnorm2 + C);                // NR*NSL       (8 MB)
  int2*   t2i    = (int2*)(t2v + (size_t)NR * NSL);      // NR*NSL       (8 MB)
  float*  commit = (float*)(t2i + (size_t)NR * NSL);     // 4
  ushort_t* ih   = (ushort_t*)(commit + 4);              // C*D bf16     (4 MB)
  ushort_t* cbh  = ih + (size_t)C * D;                   // C*D bf16     (4 MB)
  ushort_t* cbl  = cbh + (size_t)C * D;                  // C*D bf16     (4 MB)
  ushort_t* wh   = cbl + (size_t)C * D;                  // D*D bf16
  ushort_t* wl   = wh + (size_t)D * D;                   // D*D bf16

  // xh scratch in d_out's quantized region (16 MB), overwritten by k_rot
  ushort_t* xh = (ushort_t*)out;                         // NR*D bf16

  hipMemsetAsync(qnorm2, 0, C * sizeof(float), stream);
  hipMemsetAsync(commit, 0, 4 * sizeof(float), stream);

  k_cvt2<<<((C + D) * D) / (256 * 4), 256, 0, stream>>>(cb, W, cbh, cbl, wh, wl);
  k_implicit<<<dim3(C / 128, D / 128), 256, 0, stream>>>(cbh, cbl, wh, wl, imp, qnorm2, ih);
  k_cvt<<<(NR * D) / (256 * 4), 256, 0, stream>>>(x, xh);
  k_dist<<<4096, 256, 0, stream>>>(xh, ih, qnorm2, t2v, t2i);
  k_rot<<<NR / 4, 256, 0, stream>>>(x, imp, t2v, t2i, out, commit);
  k_final<<<1, 1, 0, stream>>>(commit, out);
}

// Round 19
// 380.972 us; speedup vs baseline: 1.5343x; 1.4654x over previous
//
#include <hip/hip_runtime.h>
#include <hip/hip_bf16.h>

// SimVQ: x[8,2048,512] f32, codebook[4096,512] f32, W[512,512] f32
// out (f32 flat): quantized_out[16384*512] | indices[16384] (as f32) | commit_loss[1]
//
// Round 19: r18 verbatim except commit-loss reduction de-contended:
// k_rot previously did 16384 device atomicAdds to ONE address (4 waves x
// 4096 blocks) -> serialized L2 RMW, est. 100-170 us hidden in the tail
// (and why r15's extra 'done' atomics regressed). Now: 4 wave-partials ->
// LDS -> ONE atomic per block into a 256-slot x 128B-stride buffer
// (slot = bid&255); k_final reduces the 256 slots.

typedef unsigned short ushort_t;
typedef __attribute__((ext_vector_type(8))) short bf16x8;
typedef __attribute__((ext_vector_type(4))) float f32x4;

constexpr int D  = 512;
constexpr int C  = 4096;
constexpr int NR = 16384;
constexpr int NSL = 64;             // partial slices per row (row-major)
constexpr float DELTA = 1.0f;       // top-4 fp64 rescue threshold

__device__ __forceinline__ ushort_t f2bf(float v) {
  __hip_bfloat16 h = __float2bfloat16(v);
  return *reinterpret_cast<ushort_t*>(&h);
}
__device__ __forceinline__ float bf2f(ushort_t u) {
  __hip_bfloat16 h;
  *reinterpret_cast<ushort_t*>(&h) = u;
  return __bfloat162float(h);
}

__device__ __forceinline__ void gld16(void* lds, const void* g) {
  __builtin_amdgcn_global_load_lds(
      (const __attribute__((address_space(1))) unsigned int*)g,
      (__attribute__((address_space(3))) unsigned int*)lds, 16, 0, 0);
}

__device__ __forceinline__ bool lexlt(float v, int i, float ov, int oi) {
  return v < ov || (v == ov && i < oi);
}

__device__ __forceinline__ void top2_merge(float& v1, int& i1, float& v2, int& i2,
                                           float ov1, int oi1, float ov2, int oi2) {
  if (lexlt(ov1, oi1, v1, i1)) {
    float nv2; int ni2;
    if (lexlt(v1, i1, ov2, oi2)) { nv2 = v1; ni2 = i1; }
    else { nv2 = ov2; ni2 = oi2; }
    v2 = nv2; i2 = ni2; v1 = ov1; i1 = oi1;
  } else {
    if (lexlt(ov1, oi1, v2, i2)) { v2 = ov1; i2 = oi1; }
  }
}

// ---------------- K0: split cb and W into bf16 hi/lo ----------------
__global__ __launch_bounds__(256) void k_cvt2(
    const float* __restrict__ cb, const float* __restrict__ W,
    ushort_t* __restrict__ cbh, ushort_t* __restrict__ cbl,
    ushort_t* __restrict__ wh, ushort_t* __restrict__ wl) {
  const size_t i = ((size_t)blockIdx.x * 256 + threadIdx.x) * 4;
  const size_t CD = (size_t)C * D;
  const float* src; ushort_t* dh; ushort_t* dl; size_t off;
  if (i < CD) { src = cb; dh = cbh; dl = cbl; off = i; }
  else        { src = W;  dh = wh;  dl = wl;  off = i - CD; }
  float4 v = *(const float4*)(src + off);
  ushort4 h, l;
  h.x = f2bf(v.x); l.x = f2bf(v.x - bf2f(h.x));
  h.y = f2bf(v.y); l.y = f2bf(v.y - bf2f(h.y));
  h.z = f2bf(v.z); l.z = f2bf(v.z - bf2f(h.z));
  h.w = f2bf(v.w); l.w = f2bf(v.w - bf2f(h.w));
  *(ushort4*)(dh + off) = h;
  *(ushort4*)(dl + off) = l;
}

// ---------------- K1: implicit = cb @ W^T via 3-leg split-bf16 MFMA ----------------
__global__ __launch_bounds__(256, 2) void k_implicit(
    const ushort_t* __restrict__ cbh, const ushort_t* __restrict__ cbl,
    const ushort_t* __restrict__ wh, const ushort_t* __restrict__ wl,
    float* __restrict__ imp, float* __restrict__ qnorm2,
    ushort_t* __restrict__ ih) {
  __shared__ ushort_t Ah[128 * 32], Al[128 * 32], Bh[128 * 32], Bl[128 * 32];
  const int c0 = blockIdx.x * 128;
  const int j0 = blockIdx.y * 128;
  const int t = threadIdx.x;
  const int wid = t >> 6, lane = t & 63;
  const int wr = wid >> 1, wc = wid & 1;

  const int srow = t >> 2;
  const int koff = (((t & 3) ^ ((t >> 3) & 3)) << 3);

  f32x4 acc[4][4];
#pragma unroll
  for (int m = 0; m < 4; ++m)
#pragma unroll
    for (int n = 0; n < 4; ++n) acc[m][n] = (f32x4){0.f, 0.f, 0.f, 0.f};

  char* lAh = (char*)Ah + wid * 1024;
  char* lAl = (char*)Al + wid * 1024;
  char* lBh = (char*)Bh + wid * 1024;
  char* lBl = (char*)Bl + wid * 1024;

  const int arow = wr * 64 + (lane & 15);
  const int brow = wc * 64 + (lane & 15);
  const int swz = (((lane >> 4) ^ ((lane >> 1) & 3)) << 3);

  const size_t gA0 = (size_t)(c0 + srow) * D + koff;
  const size_t gB0 = (size_t)(j0 + srow) * D + koff;

  for (int kk = 0; kk < D; kk += 32) {
    __syncthreads();
    gld16(lAh,        cbh + gA0 + kk);
    gld16(lAh + 4096, cbh + gA0 + kk + (size_t)64 * D);
    gld16(lAl,        cbl + gA0 + kk);
    gld16(lAl + 4096, cbl + gA0 + kk + (size_t)64 * D);
    gld16(lBh,        wh + gB0 + kk);
    gld16(lBh + 4096, wh + gB0 + kk + (size_t)64 * D);
    gld16(lBl,        wl + gB0 + kk);
    gld16(lBl + 4096, wl + gB0 + kk + (size_t)64 * D);
    __syncthreads();

    bf16x8 ah[4], al4[4], bh[4], bl4[4];
#pragma unroll
    for (int m = 0; m < 4; ++m) {
      ah[m]  = *(const bf16x8*)&Ah[(arow + m * 16) * 32 + swz];
      al4[m] = *(const bf16x8*)&Al[(arow + m * 16) * 32 + swz];
    }
#pragma unroll
    for (int n = 0; n < 4; ++n) {
      bh[n]  = *(const bf16x8*)&Bh[(brow + n * 16) * 32 + swz];
      bl4[n] = *(const bf16x8*)&Bl[(brow + n * 16) * 32 + swz];
    }
#pragma unroll
    for (int m = 0; m < 4; ++m)
#pragma unroll
      for (int n = 0; n < 4; ++n) {
        acc[m][n] = __builtin_amdgcn_mfma_f32_16x16x32_bf16(ah[m],  bh[n],  acc[m][n], 0, 0, 0);
        acc[m][n] = __builtin_amdgcn_mfma_f32_16x16x32_bf16(ah[m],  bl4[n], acc[m][n], 0, 0, 0);
        acc[m][n] = __builtin_amdgcn_mfma_f32_16x16x32_bf16(al4[m], bh[n],  acc[m][n], 0, 0, 0);
      }
  }

#pragma unroll
  for (int m = 0; m < 4; ++m)
#pragma unroll
    for (int r = 0; r < 4; ++r) {
      const int rowg = c0 + wr * 64 + m * 16 + (lane >> 4) * 4 + r;
      float sq = 0.f;
#pragma unroll
      for (int n = 0; n < 4; ++n) {
        const float v = acc[m][n][r];
        const int colg = j0 + wc * 64 + n * 16 + (lane & 15);
        imp[(size_t)rowg * D + colg] = v;
        ih[(size_t)rowg * D + colg] = f2bf(v);
        sq = fmaf(v, v, sq);
      }
#pragma unroll
      for (int mm = 1; mm < 16; mm <<= 1) sq += __shfl_xor(sq, mm, 64);
      if ((lane & 15) == 0) atomicAdd(&qnorm2[rowg], sq);
    }
}

// ---------------- K1b: x -> xh bf16 ----------------
__global__ __launch_bounds__(256) void k_cvt(const float* __restrict__ x,
                                             ushort_t* __restrict__ xh) {
  const size_t i = ((size_t)blockIdx.x * 256 + threadIdx.x) * 4;
  float4 v = *(const float4*)(x + i);
  ushort4 h;
  h.x = f2bf(v.x); h.y = f2bf(v.y); h.z = f2bf(v.z); h.w = f2bf(v.w);
  *(ushort4*)(xh + i) = h;
}

// ---------------- K2: 1-leg MFMA distance + fused TOP-2 argmin (round-13) ----------------
__global__ __launch_bounds__(256, 4) void k_dist(
    const ushort_t* __restrict__ xh, const ushort_t* __restrict__ ih,
    const float* __restrict__ qnorm2,
    float2* __restrict__ t2v, int2* __restrict__ t2i) {
  __shared__ ushort_t Ah[128 * 64], Bh[128 * 64];   // 16 KB each
  const int id = blockIdx.x;
  const int bx = ((id >> 8) << 3) + (id & 7);
  const int by = (id >> 3) & 31;
  const int r0 = bx * 128;
  const int c0 = by * 128;
  const int t = threadIdx.x;
  const int wid = t >> 6, lane = t & 63;
  const int wr = wid >> 1, wc = wid & 1;

  const int koff = (((t & 7) ^ ((t >> 3) & 7)) << 3);   // elems
  const size_t gA0 = (size_t)(r0 + (t >> 3)) * D + koff;
  const size_t gB0 = (size_t)(c0 + (t >> 3)) * D + koff;
  char* lA = (char*)Ah + wid * 1024;
  char* lB = (char*)Bh + wid * 1024;

  f32x4 acc[4][4];
#pragma unroll
  for (int m = 0; m < 4; ++m)
#pragma unroll
    for (int n = 0; n < 4; ++n) acc[m][n] = (f32x4){0.f, 0.f, 0.f, 0.f};

  const int arow = wr * 64 + (lane & 15);
  const int brow = wc * 64 + (lane & 15);
  const int cp0 = (((lane >> 4) ^ (lane & 7)) << 4);    // bytes

  for (int kk = 0; kk < D; kk += 64) {
    __syncthreads();
#pragma unroll
    for (int j = 0; j < 4; ++j) {
      gld16(lA + j * 4096, xh + gA0 + kk + (size_t)(32 * j) * D);
      gld16(lB + j * 4096, ih + gB0 + kk + (size_t)(32 * j) * D);
    }
    __syncthreads();

#pragma unroll
    for (int ks = 0; ks < 2; ++ks) {
      const int kx = cp0 ^ (ks << 6);
      bf16x8 a[4], b[4];
#pragma unroll
      for (int m = 0; m < 4; ++m)
        a[m] = *(const bf16x8*)((const char*)Ah + ((arow + m * 16) << 7) + kx);
#pragma unroll
      for (int n = 0; n < 4; ++n)
        b[n] = *(const bf16x8*)((const char*)Bh + ((brow + n * 16) << 7) + kx);
#pragma unroll
      for (int m = 0; m < 4; ++m)
#pragma unroll
        for (int n = 0; n < 4; ++n)
          acc[m][n] = __builtin_amdgcn_mfma_f32_16x16x32_bf16(a[m], b[n], acc[m][n], 0, 0, 0);
    }
  }

  int colg[4]; float qnv[4];
#pragma unroll
  for (int n = 0; n < 4; ++n) {
    colg[n] = c0 + wc * 64 + n * 16 + (lane & 15);
    qnv[n] = qnorm2[colg[n]];
  }
  const int sp2 = by * 2 + wc;
#pragma unroll
  for (int m = 0; m < 4; ++m)
#pragma unroll
    for (int r = 0; r < 4; ++r) {
      float v1 = fmaf(-2.f, acc[m][0][r], qnv[0]); int i1 = colg[0];
      float v2 = 3.4e38f;                          int i2 = 0x7fffffff;
#pragma unroll
      for (int n = 1; n < 4; ++n) {
        const float s = fmaf(-2.f, acc[m][n][r], qnv[n]);
        const int   c = colg[n];
        if (lexlt(s, c, v1, i1)) { v2 = v1; i2 = i1; v1 = s; i1 = c; }
        else if (lexlt(s, c, v2, i2)) { v2 = s; i2 = c; }
      }
#pragma unroll
      for (int off = 1; off < 16; off <<= 1) {
        const float ov1 = __shfl_xor(v1, off, 64);
        const int   oi1 = __shfl_xor(i1, off, 64);
        const float ov2 = __shfl_xor(v2, off, 64);
        const int   oi2 = __shfl_xor(i2, off, 64);
        top2_merge(v1, i1, v2, i2, ov1, oi1, ov2, oi2);
      }
      if ((lane & 15) == 0) {
        const int row = r0 + wr * 64 + m * 16 + (lane >> 4) * 4 + r;
        t2v[(size_t)row * NSL + sp2] = make_float2(v1, v2);
        t2i[(size_t)row * NSL + sp2] = make_int2(i1, i2);
      }
    }
}

// compare-exchange ascending (lex) on named scalars
#define CE(vx, ix, vy, iy)                                        \
  do {                                                            \
    if (lexlt(vy, iy, vx, ix)) {                                  \
      float tv = vx; int ti = ix;                                 \
      vx = vy; ix = iy; vy = tv; iy = ti;                         \
    }                                                             \
  } while (0)

// ---------------- K3: wave-per-row top-4 merge + fp64 rescore + rotation ----------------
// Commit partials: 4 wave values -> LDS -> ONE atomic per block into a
// 256-slot x 32-float-stride buffer (slot = bid & 255).
__global__ __launch_bounds__(256) void k_rot(
    const float* __restrict__ x, const float* __restrict__ imp,
    const float2* __restrict__ t2v, const int2* __restrict__ t2i,
    float* __restrict__ out, float* __restrict__ commit_acc) {
  const int tid = threadIdx.x;
  const int wid = tid >> 6, lane = tid & 63;
  const int row = blockIdx.x * 4 + wid;
  __shared__ float sred[4];

  const float2 vv = t2v[(size_t)row * NSL + lane];
  const int2   ii = t2i[(size_t)row * NSL + lane];
  float a0 = vv.x, a1 = vv.y, a2 = 3.4e38f, a3 = 3.4e38f;
  int   j0 = ii.x, j1 = ii.y, j2 = 0x7fffffff, j3 = 0x7fffffff;
#pragma unroll
  for (int off = 1; off < 64; off <<= 1) {
    const float b0 = __shfl_xor(a0, off, 64), b1 = __shfl_xor(a1, off, 64);
    const float b2 = __shfl_xor(a2, off, 64), b3 = __shfl_xor(a3, off, 64);
    const int   k0 = __shfl_xor(j0, off, 64), k1 = __shfl_xor(j1, off, 64);
    const int   k2 = __shfl_xor(j2, off, 64), k3 = __shfl_xor(j3, off, 64);
    float m0 = a0, m1 = a1, m2 = a2, m3 = a3;
    int   n0 = j0, n1 = j1, n2 = j2, n3 = j3;
    if (lexlt(b3, k3, m0, n0)) { m0 = b3; n0 = k3; }
    if (lexlt(b2, k2, m1, n1)) { m1 = b2; n1 = k2; }
    if (lexlt(b1, k1, m2, n2)) { m2 = b1; n2 = k1; }
    if (lexlt(b0, k0, m3, n3)) { m3 = b0; n3 = k0; }
    CE(m0, n0, m2, n2); CE(m1, n1, m3, n3);
    CE(m0, n0, m1, n1); CE(m2, n2, m3, n3);
    a0 = m0; a1 = m1; a2 = m2; a3 = m3;
    j0 = n0; j1 = n1; j2 = n2; j3 = n3;
  }
  const bool need = (a1 - a0 < DELTA);

  const float* xr = x + (size_t)row * D + lane * 8;
  const float4 xa = *(const float4*)(xr);
  const float4 xb = *(const float4*)(xr + 4);
  const float xs[8] = {xa.x, xa.y, xa.z, xa.w, xb.x, xb.y, xb.z, xb.w};

  int bi = j0;
  if (need) {
    double s0 = 0.0, s1 = 0.0, s2 = 0.0, s3 = 0.0;
    {
      const float* q0 = imp + (size_t)j0 * D + lane * 8;
      const float* q1 = imp + (size_t)j1 * D + lane * 8;
      const float* q2 = imp + (size_t)j2 * D + lane * 8;
      const float* q3 = imp + (size_t)j3 * D + lane * 8;
      const float4 q0a = *(const float4*)(q0), q0b = *(const float4*)(q0 + 4);
      const float4 q1a = *(const float4*)(q1), q1b = *(const float4*)(q1 + 4);
      const float4 q2a = *(const float4*)(q2), q2b = *(const float4*)(q2 + 4);
      const float4 q3a = *(const float4*)(q3), q3b = *(const float4*)(q3 + 4);
      const float q0s[8] = {q0a.x, q0a.y, q0a.z, q0a.w, q0b.x, q0b.y, q0b.z, q0b.w};
      const float q1s[8] = {q1a.x, q1a.y, q1a.z, q1a.w, q1b.x, q1b.y, q1b.z, q1b.w};
      const float q2s[8] = {q2a.x, q2a.y, q2a.z, q2a.w, q2b.x, q2b.y, q2b.z, q2b.w};
      const float q3s[8] = {q3a.x, q3a.y, q3a.z, q3a.w, q3b.x, q3b.y, q3b.z, q3b.w};
#pragma unroll
      for (int e = 0; e < 8; ++e) {
        const double xe = (double)xs[e];
        double d;
        d = xe - (double)q0s[e]; s0 += d * d;
        d = xe - (double)q1s[e]; s1 += d * d;
        d = xe - (double)q2s[e]; s2 += d * d;
        d = xe - (double)q3s[e]; s3 += d * d;
      }
    }
#pragma unroll
    for (int m = 1; m < 64; m <<= 1) {
      s0 += __shfl_xor(s0, m, 64);
      s1 += __shfl_xor(s1, m, 64);
      s2 += __shfl_xor(s2, m, 64);
      s3 += __shfl_xor(s3, m, 64);
    }
    double bd = s0; bi = j0;
    if (s1 < bd || (s1 == bd && j1 < bi)) { bd = s1; bi = j1; }
    if (s2 < bd || (s2 == bd && j2 < bi)) { bd = s2; bi = j2; }
    if (s3 < bd || (s3 == bd && j3 < bi)) { bd = s3; bi = j3; }
  }

  const float* qr = imp + (size_t)bi * D + lane * 8;
  const float4 qa4 = *(const float4*)(qr);
  const float4 qb4 = *(const float4*)(qr + 4);
  const float qs[8] = {qa4.x, qa4.y, qa4.z, qa4.w, qb4.x, qb4.y, qb4.z, qb4.w};

  float sx2 = 0.f, sq2 = 0.f, sxq = 0.f, scm = 0.f;
#pragma unroll
  for (int e = 0; e < 8; ++e) {
    sx2 = fmaf(xs[e], xs[e], sx2);
    sq2 = fmaf(qs[e], qs[e], sq2);
    sxq = fmaf(xs[e], qs[e], sxq);
    const float de = xs[e] - qs[e] + 1e-6f;
    scm = fmaf(de, de, scm);
  }
#pragma unroll
  for (int m = 1; m < 64; m <<= 1) {
    sx2 += __shfl_xor(sx2, m, 64);
    sq2 += __shfl_xor(sq2, m, 64);
    sxq += __shfl_xor(sxq, m, 64);
    scm += __shfl_xor(scm, m, 64);
  }

  const float norm_x = sqrtf(sx2), norm_q = sqrtf(sq2);
  const float cnx = fmaxf(norm_x, 1e-6f), cnq = fmaxf(norm_q, 1e-6f);
  const float inx = 1.0f / cnx, inq = 1.0f / cnq;
  const float nuq2 = sx2 * inx * inx + 2.0f * sxq * inx * inq + sq2 * inq * inq;
  const float iw = 1.0f / fmaxf(sqrtf(nuq2), 1e-12f);
  const float e_dot_u = sx2 * inx;
  const float e_dot_w = (sx2 * inx + sxq * inq) * iw;
  const float scale = norm_q * inx;

  float os[8];
#pragma unroll
  for (int e = 0; e < 8; ++e) {
    const float we = (xs[e] * inx + qs[e] * inq) * iw;
    float re = xs[e] - 2.0f * e_dot_w * we;
    re = fmaf(2.0f * e_dot_u, qs[e] * inq, re);
    os[e] = re * scale;
  }
  float* op = out + (size_t)row * D + lane * 8;
  *(float4*)(op)     = make_float4(os[0], os[1], os[2], os[3]);
  *(float4*)(op + 4) = make_float4(os[4], os[5], os[6], os[7]);

  if (lane == 0) {
    sred[wid] = scm;
    out[(size_t)NR * D + row] = (float)bi;
  }
  __syncthreads();
  if (tid == 0) {
    const float tot = (sred[0] + sred[1]) + (sred[2] + sred[3]);
    atomicAdd(&commit_acc[(blockIdx.x & 255) << 5], tot);
  }
}
#undef CE

// ---------------- K4: finalize commit loss (reduce 256 slots) ----------------
__global__ __launch_bounds__(256) void k_final(const float* __restrict__ commit_acc,
                                               float* __restrict__ out) {
  const int tid = threadIdx.x;
  float v = commit_acc[tid << 5];
#pragma unroll
  for (int m = 1; m < 64; m <<= 1) v += __shfl_xor(v, m, 64);
  __shared__ float s[4];
  if ((tid & 63) == 0) s[tid >> 6] = v;
  __syncthreads();
  if (tid == 0)
    out[(size_t)NR * D + NR] = ((s[0] + s[1]) + (s[2] + s[3])) * (1.0f / (float)NR);
}

extern "C" void kernel_launch(void* const* d_in, const int* in_sizes, int n_in,
                              void* d_out, int out_size, void* d_ws, size_t ws_size,
                              hipStream_t stream) {
  const float* x  = (const float*)d_in[0];
  const float* cb = (const float*)d_in[1];
  const float* W  = (const float*)d_in[2];
  float* out = (float*)d_out;

  float* ws     = (float*)d_ws;
  float*  imp    = ws;                                   // C*D f32      (8 MB)
  float*  qnorm2 = imp + (size_t)C * D;                  // C
  float2* t2v    = (float2*)(qnorm2 + C);                // NR*NSL       (8 MB)
  int2*   t2i    = (int2*)(t2v + (size_t)NR * NSL);      // NR*NSL       (8 MB)
  float*  commit = (float*)(t2i + (size_t)NR * NSL);     // 256 slots x 32 f (32 KB)
  ushort_t* ih   = (ushort_t*)(commit + 256 * 32);       // C*D bf16     (4 MB)
  ushort_t* cbh  = ih + (size_t)C * D;                   // C*D bf16     (4 MB)
  ushort_t* cbl  = cbh + (size_t)C * D;                  // C*D bf16     (4 MB)
  ushort_t* wh   = cbl + (size_t)C * D;                  // D*D bf16
  ushort_t* wl   = wh + (size_t)D * D;                   // D*D bf16

  // xh scratch in d_out's quantized region (16 MB), overwritten by k_rot
  ushort_t* xh = (ushort_t*)out;                         // NR*D bf16

  hipMemsetAsync(qnorm2, 0, C * sizeof(float), stream);
  hipMemsetAsync(commit, 0, 256 * 32 * sizeof(float), stream);

  k_cvt2<<<((C + D) * D) / (256 * 4), 256, 0, stream>>>(cb, W, cbh, cbl, wh, wl);
  k_implicit<<<dim3(C / 128, D / 128), 256, 0, stream>>>(cbh, cbl, wh, wl, imp, qnorm2, ih);
  k_cvt<<<(NR * D) / (256 * 4), 256, 0, stream>>>(x, xh);
  k_dist<<<4096, 256, 0, stream>>>(xh, ih, qnorm2, t2v, t2i);
  k_rot<<<NR / 4, 256, 0, stream>>>(x, imp, t2v, t2i, out, commit);
  k_final<<<1, 256, 0, stream>>>(commit, out);
}